// Round 1
// baseline (61.487 us; speedup 1.0000x reference)
//
#include <hip/hip_runtime.h>
#include <stdint.h>

#define BB 512
#define NN 8192
#define KK 16
#define HH 16

// ---------------------------------------------------------------------------
// Kernel 1: pack x (B,N) fp32 of +-1 into transposed bitmask.
// xp[w*N + j] : bit i set iff x[(w*32+i)*N + j] > 0.  Size = 16*8192*4 = 512KB.
// Lanes have consecutive j -> all 32 x-loads are coalesced (row segments).
// ---------------------------------------------------------------------------
__global__ __launch_bounds__(256) void pack_kernel(const float* __restrict__ x,
                                                   uint32_t* __restrict__ xp) {
    const int j = blockIdx.x * 256 + threadIdx.x;
    const int w = blockIdx.y;
    uint32_t word = 0u;
#pragma unroll
    for (int i = 0; i < 32; ++i) {
        float v = x[(size_t)(w * 32 + i) * NN + j];
        word |= (v > 0.0f ? 1u : 0u) << i;
    }
    xp[(size_t)w * NN + j] = word;
}

// ---------------------------------------------------------------------------
// Kernel 2: one block per n (grid = 8192), 512 threads = one b each.
// Sign bits gathered from L2-resident bitmask (uniform-ish 4B loads);
// W1/b1/W2/b2 addresses are blockIdx-uniform -> scalar loads; inner loop is
// 256 v_fma_f32 with SGPR W operand per thread.
// PACKED=false falls back to direct (uncoalesced) x gathers.
// TOUT=true stores coalesced to outT[n*B+b]; else direct out[b*N+n].
// ---------------------------------------------------------------------------
template <bool PACKED, bool TOUT>
__global__ __launch_bounds__(512) void main_kernel(
    const uint32_t* __restrict__ xp, const float* __restrict__ x,
    const int* __restrict__ neighs, const float* __restrict__ W1,
    const float* __restrict__ b1, const float* __restrict__ W2,
    const float* __restrict__ b2, float* __restrict__ outp) {
    const int n = blockIdx.x;
    const int b = threadIdx.x;
    const int w = b >> 5;
    const int bit = b & 31;

    const int* nb = neighs + n * KK;          // uniform
    const float* W1n = W1 + (size_t)n * KK * HH; // uniform
    const float* b1n = b1 + (size_t)n * HH;      // uniform
    const float* W2n = W2 + (size_t)n * HH;      // uniform

    // Gather all 16 signs up front (independent loads, latency overlapped).
    float s[KK];
#pragma unroll
    for (int k = 0; k < KK; ++k) {
        const int j = nb[k];
        float sv;
        if (PACKED) {
            const uint32_t wd = xp[(size_t)w * NN + j];
            sv = ((wd >> bit) & 1u) ? 1.0f : -1.0f;
        } else {
            sv = x[(size_t)b * NN + j];
        }
        s[k] = sv;
    }

    float acc[HH];
#pragma unroll
    for (int h = 0; h < HH; ++h) acc[h] = b1n[h];

#pragma unroll
    for (int k = 0; k < KK; ++k) {
#pragma unroll
        for (int h = 0; h < HH; ++h)
            acc[h] = fmaf(s[k], W1n[k * HH + h], acc[h]);
    }

    float z = b2[n];
#pragma unroll
    for (int h = 0; h < HH; ++h)
        z = fmaf(fmaxf(acc[h], 0.0f), W2n[h], z);

    const float r = 1.0f / (1.0f + __expf(-z));
    if (TOUT)
        outp[(size_t)n * BB + b] = r;       // coalesced
    else
        outp[(size_t)b * NN + n] = r;       // fallback, uncoalesced
}

// ---------------------------------------------------------------------------
// Kernel 3: transpose outT (N,B) -> out (B,N) via 64x64 LDS tile.
// ---------------------------------------------------------------------------
__global__ __launch_bounds__(256) void transpose_kernel(
    const float* __restrict__ outT, float* __restrict__ out) {
    __shared__ float tile[64][65];
    const int n0 = blockIdx.x * 64;
    const int b0 = blockIdx.y * 64;
    const int tx = threadIdx.x & 63;
    const int ty = threadIdx.x >> 6;  // 0..3
#pragma unroll
    for (int i = 0; i < 16; ++i) {
        const int nrow = ty + i * 4;
        tile[nrow][tx] = outT[(size_t)(n0 + nrow) * BB + b0 + tx];
    }
    __syncthreads();
#pragma unroll
    for (int i = 0; i < 16; ++i) {
        const int brow = ty + i * 4;
        out[(size_t)(b0 + brow) * NN + n0 + tx] = tile[tx][brow];
    }
}

extern "C" void kernel_launch(void* const* d_in, const int* in_sizes, int n_in,
                              void* d_out, int out_size, void* d_ws, size_t ws_size,
                              hipStream_t stream) {
    const float* x      = (const float*)d_in[0];
    const int*   neighs = (const int*)d_in[1];
    const float* W1     = (const float*)d_in[2];
    const float* b1     = (const float*)d_in[3];
    const float* W2     = (const float*)d_in[4];
    const float* b2     = (const float*)d_in[5];
    float* out = (float*)d_out;

    const size_t pack_bytes = (size_t)(BB / 32) * NN * sizeof(uint32_t); // 512 KB
    const size_t outT_bytes = (size_t)BB * NN * sizeof(float);           // 16 MB
    const bool have_pack = ws_size >= pack_bytes;
    const bool have_outT = ws_size >= pack_bytes + outT_bytes;

    if (have_pack) {
        uint32_t* xp = (uint32_t*)d_ws;
        pack_kernel<<<dim3(NN / 256, BB / 32), 256, 0, stream>>>(x, xp);
        if (have_outT) {
            float* outT = (float*)((char*)d_ws + pack_bytes);
            main_kernel<true, true><<<NN, BB, 0, stream>>>(
                xp, x, neighs, W1, b1, W2, b2, outT);
            transpose_kernel<<<dim3(NN / 64, BB / 64), 256, 0, stream>>>(outT, out);
        } else {
            main_kernel<true, false><<<NN, BB, 0, stream>>>(
                xp, x, neighs, W1, b1, W2, b2, out);
        }
    } else {
        main_kernel<false, false><<<NN, BB, 0, stream>>>(
            nullptr, x, neighs, W1, b1, W2, b2, out);
    }
}

// Round 2
// 46.732 us; speedup vs baseline: 1.3157x; 1.3157x over previous
//
#include <hip/hip_runtime.h>
#include <stdint.h>

#define BB 512
#define NN 8192
#define KK 16
#define HH 16

typedef short bf16x8 __attribute__((ext_vector_type(8)));
typedef float f32x4  __attribute__((ext_vector_type(4)));
typedef uint32_t u32x4 __attribute__((ext_vector_type(4)));

__device__ __forceinline__ uint32_t f2bf(float f) {
    // round-to-nearest-even f32 -> bf16 (no NaN in this data)
    uint32_t u = __builtin_bit_cast(uint32_t, f);
    return (u + 0x7FFFu + ((u >> 16) & 1u)) >> 16;
}

// ---------------------------------------------------------------------------
// Kernel 1: pack x (B,N) fp32 of +-1 into transposed bitmask.
// xp[w*N + j] : bit i set iff x[(w*32+i)*N + j] > 0.  512 KB, L2-resident.
// ---------------------------------------------------------------------------
__global__ __launch_bounds__(256) void pack_kernel(const float* __restrict__ x,
                                                   uint32_t* __restrict__ xp) {
    const int j = blockIdx.x * 256 + threadIdx.x;
    const int w = blockIdx.y;
    uint32_t word = 0u;
#pragma unroll
    for (int i = 0; i < 32; ++i) {
        float v = x[(size_t)(w * 32 + i) * NN + j];
        word |= (v > 0.0f ? 1u : 0u) << i;
    }
    xp[(size_t)w * NN + j] = word;
}

// ---------------------------------------------------------------------------
// Kernel 2 (MFMA): one block per n, 8 waves; each wave owns 64 b-rows
// (4 tiles of 16).  D[h][b] = W1^T . s^T via mfma_f32_16x16x32_bf16 (K=16
// zero-padded).  A-frag = W1^T bf16 (lanes 0-31), built once per wave.
// B-frag = signs, built from bit-packed xp words staged in LDS (one 32-bit
// word holds all 16 rows' bits for a given k).  Stage 2 = 4 fma + 2 shfl_xor.
// Output coalesced to outT[n][b]; transposed afterwards.
// ---------------------------------------------------------------------------
__global__ __launch_bounds__(512, 4) void mfma_kernel(
    const uint32_t* __restrict__ xp, const int* __restrict__ neighs,
    const float* __restrict__ W1, const float* __restrict__ b1,
    const float* __restrict__ W2, const float* __restrict__ b2,
    float* __restrict__ outT) {
    const int n   = blockIdx.x;
    const int tid = threadIdx.x;
    const int wv  = tid >> 6;     // wave 0..7
    const int l   = tid & 63;
    const int l15 = l & 15;
    const int lg  = l >> 4;       // 0..3

    __shared__ __align__(16) uint32_t lds_w[8 * 32];  // [wave][wsel][k]

    // ---- prep: gather this wave's 32 xp words (2 w-groups x 16 k) ----
    if (l < 32) {
        const int k    = l15;
        const int wsel = lg & 1;
        const int j    = neighs[n * KK + k];
        lds_w[wv * 32 + wsel * 16 + k] = xp[(wv * 2 + wsel) * NN + j];
    }

    // ---- A-frag: A[h=l15][k=lg*8+r] = W1[n][k][h], zero for k>=16 ----
    const float* W1n = W1 + (size_t)n * (KK * HH);
    uint32_t aw[4] = {0u, 0u, 0u, 0u};
    if (l < 32) {
        const int kbase = lg * 8;
#pragma unroll
        for (int i = 0; i < 4; ++i) {
            const float f0 = W1n[(kbase + 2 * i)     * HH + l15];
            const float f1 = W1n[(kbase + 2 * i + 1) * HH + l15];
            aw[i] = f2bf(f0) | (f2bf(f1) << 16);
        }
    }
    const u32x4 av = {aw[0], aw[1], aw[2], aw[3]};
    const bf16x8 afrag = __builtin_bit_cast(bf16x8, av);

    // C init with b1 (C rows are h): acc[r] = b1[n][lg*4+r]
    const float4 b1v = *(const float4*)(b1 + (size_t)n * HH + lg * 4);
    const f32x4 accInit = {b1v.x, b1v.y, b1v.z, b1v.w};
    const float4 w2v4 = *(const float4*)(W2 + (size_t)n * HH + lg * 4);
    const float w2r[4] = {w2v4.x, w2v4.y, w2v4.z, w2v4.w};
    const float b2n = b2[n];

#pragma unroll
    for (int g = 0; g < 2; ++g) {  // two 32-row groups (tiles 2g, 2g+1)
        const uint32_t* p = &lds_w[wv * 32 + g * 16 + (lg & 1) * 8];
        const uint4 wa = *(const uint4*)(p);
        const uint4 wb = *(const uint4*)(p + 4);
        const uint32_t wk[8] = {wa.x, wa.y, wa.z, wa.w, wb.x, wb.y, wb.z, wb.w};

        f32x4 acc[2];
#pragma unroll
        for (int o = 0; o < 2; ++o) {
            const int pos = o * 16 + l15;  // bit position within the word
            u32x4 bd;
#pragma unroll
            for (int i = 0; i < 4; ++i) {
                const uint32_t s0 = (wk[2 * i]     >> pos) & 1u;
                const uint32_t s1 = (wk[2 * i + 1] >> pos) & 1u;
                // bit=1 -> +1.0bf16 (0x3F80), bit=0 -> -1.0bf16 (0xBF80)
                bd[i] = 0xBF80BF80u ^ (s0 << 15) ^ (s1 << 31);
            }
            const bf16x8 bfrag = __builtin_bit_cast(bf16x8, bd);
            acc[o] = __builtin_amdgcn_mfma_f32_16x16x32_bf16(afrag, bfrag,
                                                             accInit, 0, 0, 0);
        }

#pragma unroll
        for (int o = 0; o < 2; ++o) {
            float z = 0.0f;
#pragma unroll
            for (int r = 0; r < 4; ++r)
                z = fmaf(fmaxf(acc[o][r], 0.0f), w2r[r], z);
            z += __shfl_xor(z, 16);
            z += __shfl_xor(z, 32);
            z += b2n;
            const float res = 1.0f / (1.0f + __expf(-z));
            const int t = 2 * g + o;
            if (l < 16)
                outT[(size_t)n * BB + wv * 64 + t * 16 + l] = res;
        }
    }
}

// ---------------------------------------------------------------------------
// Fallback scalar kernel (only used if workspace is too small).
// ---------------------------------------------------------------------------
__global__ __launch_bounds__(512) void scalar_kernel(
    const float* __restrict__ x, const int* __restrict__ neighs,
    const float* __restrict__ W1, const float* __restrict__ b1,
    const float* __restrict__ W2, const float* __restrict__ b2,
    float* __restrict__ outp) {
    const int n = blockIdx.x;
    const int b = threadIdx.x;
    const int* nb = neighs + n * KK;
    const float* W1n = W1 + (size_t)n * KK * HH;
    const float* b1n = b1 + (size_t)n * HH;
    const float* W2n = W2 + (size_t)n * HH;

    float s[KK];
#pragma unroll
    for (int k = 0; k < KK; ++k) s[k] = x[(size_t)b * NN + nb[k]];

    float acc[HH];
#pragma unroll
    for (int h = 0; h < HH; ++h) acc[h] = b1n[h];
#pragma unroll
    for (int k = 0; k < KK; ++k)
#pragma unroll
        for (int h = 0; h < HH; ++h)
            acc[h] = fmaf(s[k], W1n[k * HH + h], acc[h]);

    float z = b2[n];
#pragma unroll
    for (int h = 0; h < HH; ++h)
        z = fmaf(fmaxf(acc[h], 0.0f), W2n[h], z);
    outp[(size_t)b * NN + n] = 1.0f / (1.0f + __expf(-z));
}

// ---------------------------------------------------------------------------
// Kernel 3: transpose outT (N,B) -> out (B,N) via 64x64 LDS tile.
// ---------------------------------------------------------------------------
__global__ __launch_bounds__(256) void transpose_kernel(
    const float* __restrict__ outT, float* __restrict__ out) {
    __shared__ float tile[64][65];
    const int n0 = blockIdx.x * 64;
    const int b0 = blockIdx.y * 64;
    const int tx = threadIdx.x & 63;
    const int ty = threadIdx.x >> 6;  // 0..3
#pragma unroll
    for (int i = 0; i < 16; ++i) {
        const int nrow = ty + i * 4;
        tile[nrow][tx] = outT[(size_t)(n0 + nrow) * BB + b0 + tx];
    }
    __syncthreads();
#pragma unroll
    for (int i = 0; i < 16; ++i) {
        const int brow = ty + i * 4;
        out[(size_t)(b0 + brow) * NN + n0 + tx] = tile[tx][brow];
    }
}

extern "C" void kernel_launch(void* const* d_in, const int* in_sizes, int n_in,
                              void* d_out, int out_size, void* d_ws, size_t ws_size,
                              hipStream_t stream) {
    const float* x      = (const float*)d_in[0];
    const int*   neighs = (const int*)d_in[1];
    const float* W1     = (const float*)d_in[2];
    const float* b1     = (const float*)d_in[3];
    const float* W2     = (const float*)d_in[4];
    const float* b2     = (const float*)d_in[5];
    float* out = (float*)d_out;

    const size_t pack_bytes = (size_t)(BB / 32) * NN * sizeof(uint32_t); // 512 KB
    const size_t outT_bytes = (size_t)BB * NN * sizeof(float);           // 16 MB

    if (ws_size >= pack_bytes + outT_bytes) {
        uint32_t* xp  = (uint32_t*)d_ws;
        float* outT   = (float*)((char*)d_ws + pack_bytes);
        pack_kernel<<<dim3(NN / 256, BB / 32), 256, 0, stream>>>(x, xp);
        mfma_kernel<<<NN, 512, 0, stream>>>(xp, neighs, W1, b1, W2, b2, outT);
        transpose_kernel<<<dim3(NN / 64, BB / 64), 256, 0, stream>>>(outT, out);
    } else {
        scalar_kernel<<<NN, BB, 0, stream>>>(x, neighs, W1, b1, W2, b2, out);
    }
}

// Round 3
// 46.580 us; speedup vs baseline: 1.3200x; 1.0033x over previous
//
#include <hip/hip_runtime.h>
#include <stdint.h>

#define BB 512
#define NN 8192
#define KK 16
#define HH 16

typedef _Float16 f16;
typedef _Float16 f16x4 __attribute__((ext_vector_type(4)));
typedef float f32x4 __attribute__((ext_vector_type(4)));

// ---------------------------------------------------------------------------
// Kernel 1: transpose x (B,N) f32 -> xT (N,B) f16.  8 MB, L3-resident.
// (+-1.0 is exact in f16.)
// ---------------------------------------------------------------------------
__global__ __launch_bounds__(256) void xpose_kernel(const float* __restrict__ x,
                                                    f16* __restrict__ xT) {
    __shared__ float tile[64][65];
    const int j0 = blockIdx.x * 64;
    const int b0 = blockIdx.y * 64;
    const int c  = threadIdx.x & 63;
    const int r4 = threadIdx.x >> 6;  // 0..3
#pragma unroll
    for (int i = 0; i < 16; ++i) {
        const int b = r4 + i * 4;
        tile[b][c] = x[(size_t)(b0 + b) * NN + j0 + c];
    }
    __syncthreads();
#pragma unroll
    for (int i = 0; i < 16; ++i) {
        const int j = r4 + i * 4;
        xT[(size_t)(j0 + j) * BB + b0 + c] = (f16)tile[c][j];
    }
}

// ---------------------------------------------------------------------------
// Kernel 2: block = 64 n x 64 b, 8 waves; wave owns 8 n's x all 64 b.
// Per (n, b-tile16): D[h][b] = W1^T . s^T via mfma_f32_16x16x16_f16 (K=16
// exact).  A-frag = W1^T in f16 (4 strided loads).  B-frag = 4 f16 gathers
// from xT with wave-uniform j bases + imm tile offsets.  Stage 2 = 4 fma +
// 2 shfl_xor + sigmoid.  Results staged in padded LDS tile, stored as
// coalesced float4 rows of out[b][n] (transpose fused).
// ---------------------------------------------------------------------------
__global__ __launch_bounds__(512, 4) void mfma_kernel(
    const f16* __restrict__ xT, const int* __restrict__ neighs,
    const float* __restrict__ W1, const float* __restrict__ b1,
    const float* __restrict__ W2, const float* __restrict__ b2,
    float* __restrict__ out) {
    __shared__ float tile[64][68];  // stride 68 floats: 16B-aligned rows
    const int n0  = blockIdx.x * 64;
    const int b0  = blockIdx.y * 64;
    const int tid = threadIdx.x;
    const int wv  = tid >> 6;   // 0..7
    const int l   = tid & 63;
    const int l15 = l & 15;
    const int lg  = l >> 4;     // 0..3

#pragma unroll
    for (int ni = 0; ni < 8; ++ni) {
        const int n = n0 + wv * 8 + ni;

        // neighbor quad for this lane group (wave-uniform per lg)
        const int4 nb = *(const int4*)(neighs + n * KK + lg * 4);
        const f16* p0 = xT + (size_t)nb.x * BB + b0 + l15;
        const f16* p1 = xT + (size_t)nb.y * BB + b0 + l15;
        const f16* p2 = xT + (size_t)nb.z * BB + b0 + l15;
        const f16* p3 = xT + (size_t)nb.w * BB + b0 + l15;

        // A-frag: a[i] = W1[n][lg*4+i][l15]  (A[h][k] = W1[k][h])
        const float* W1n = W1 + (size_t)n * (KK * HH) + lg * 4 * HH + l15;
        f16x4 a;
#pragma unroll
        for (int i = 0; i < 4; ++i) a[i] = (f16)W1n[i * HH];

        const float4 b1v = *(const float4*)(b1 + (size_t)n * HH + lg * 4);
        const f32x4 cinit = {b1v.x, b1v.y, b1v.z, b1v.w};
        const float4 w2v = *(const float4*)(W2 + (size_t)n * HH + lg * 4);
        const float b2n = b2[n];

#pragma unroll
        for (int tb = 0; tb < 4; ++tb) {
            const f16x4 bfr = {p0[tb * 16], p1[tb * 16], p2[tb * 16], p3[tb * 16]};
            const f32x4 acc =
                __builtin_amdgcn_mfma_f32_16x16x16f16(a, bfr, cinit, 0, 0, 0);
            float z = fmaf(fmaxf(acc[0], 0.f), w2v.x,
                      fmaf(fmaxf(acc[1], 0.f), w2v.y,
                      fmaf(fmaxf(acc[2], 0.f), w2v.z,
                           fmaxf(acc[3], 0.f) * w2v.w)));
            z += __shfl_xor(z, 16);
            z += __shfl_xor(z, 32);
            z += b2n;
            const float r = __builtin_amdgcn_rcpf(1.0f + __expf(-z));
            if (l < 16) tile[tb * 16 + l][wv * 8 + ni] = r;
        }
    }
    __syncthreads();

    // coalesced store: 16-lane groups write 256B rows of out[b][n0..n0+63]
#pragma unroll
    for (int it = 0; it < 2; ++it) {
        const int bl = (tid >> 4) + it * 32;
        const int cg = tid & 15;
        const float4 v = *(const float4*)(&tile[bl][cg * 4]);
        *(float4*)(out + (size_t)(b0 + bl) * NN + n0 + cg * 4) = v;
    }
}

// ---------------------------------------------------------------------------
// Fallback scalar kernel (only if workspace is too small).
// ---------------------------------------------------------------------------
__global__ __launch_bounds__(512) void scalar_kernel(
    const float* __restrict__ x, const int* __restrict__ neighs,
    const float* __restrict__ W1, const float* __restrict__ b1,
    const float* __restrict__ W2, const float* __restrict__ b2,
    float* __restrict__ outp) {
    const int n = blockIdx.x;
    const int b = threadIdx.x;
    const int* nb = neighs + n * KK;
    const float* W1n = W1 + (size_t)n * KK * HH;
    const float* b1n = b1 + (size_t)n * HH;
    const float* W2n = W2 + (size_t)n * HH;

    float s[KK];
#pragma unroll
    for (int k = 0; k < KK; ++k) s[k] = x[(size_t)b * NN + nb[k]];

    float acc[HH];
#pragma unroll
    for (int h = 0; h < HH; ++h) acc[h] = b1n[h];
#pragma unroll
    for (int k = 0; k < KK; ++k)
#pragma unroll
        for (int h = 0; h < HH; ++h)
            acc[h] = fmaf(s[k], W1n[k * HH + h], acc[h]);

    float z = b2[n];
#pragma unroll
    for (int h = 0; h < HH; ++h)
        z = fmaf(fmaxf(acc[h], 0.0f), W2n[h], z);
    outp[(size_t)b * NN + n] = 1.0f / (1.0f + __expf(-z));
}

extern "C" void kernel_launch(void* const* d_in, const int* in_sizes, int n_in,
                              void* d_out, int out_size, void* d_ws, size_t ws_size,
                              hipStream_t stream) {
    const float* x      = (const float*)d_in[0];
    const int*   neighs = (const int*)d_in[1];
    const float* W1     = (const float*)d_in[2];
    const float* b1     = (const float*)d_in[3];
    const float* W2     = (const float*)d_in[4];
    const float* b2     = (const float*)d_in[5];
    float* out = (float*)d_out;

    const size_t xT_bytes = (size_t)NN * BB * sizeof(f16);  // 8 MB

    if (ws_size >= xT_bytes) {
        f16* xT = (f16*)d_ws;
        xpose_kernel<<<dim3(NN / 64, BB / 64), 256, 0, stream>>>(x, xT);
        mfma_kernel<<<dim3(NN / 64, BB / 64), 512, 0, stream>>>(
            xT, neighs, W1, b1, W2, b2, out);
    } else {
        scalar_kernel<<<NN, BB, 0, stream>>>(x, neighs, W1, b1, W2, b2, out);
    }
}

// Round 4
// 31.132 us; speedup vs baseline: 1.9751x; 1.4962x over previous
//
#include <hip/hip_runtime.h>
#include <stdint.h>

#define BB 512
#define NN 8192
#define KK 16
#define HH 16

typedef _Float16 f16;
typedef _Float16 f16x4 __attribute__((ext_vector_type(4)));
typedef float f32x4 __attribute__((ext_vector_type(4)));
typedef uint32_t u32x2 __attribute__((ext_vector_type(2)));

// ---------------------------------------------------------------------------
// Kernel 1: pack signs of x (+-1) into transposed-word bitmask.
// xpT[j*16 + w] bit i = (x[(w*32+i)*N + j] > 0).  512 KB, L2-resident.
// Reads coalesced (lanes span j); the 16 words of one j-row are contiguous
// (64B line) so the main kernel's per-n word loads have perfect locality.
// ---------------------------------------------------------------------------
__global__ __launch_bounds__(256) void pack_kernel(const float* __restrict__ x,
                                                   uint32_t* __restrict__ xpT) {
    const int j = blockIdx.x * 256 + threadIdx.x;
    const int w = blockIdx.y;
    uint32_t word = 0u;
#pragma unroll
    for (int i = 0; i < 32; ++i)
        word |= (x[(size_t)(w * 32 + i) * NN + j] > 0.0f ? 1u : 0u) << i;
    xpT[(size_t)j * 16 + w] = word;
}

// ---------------------------------------------------------------------------
// Kernel 2: block = 16 n x 64 b, 4 waves; each wave owns 4 n x 64 b.
// Per n: one 32-lane load of sign-words -> wave-private LDS (no barriers),
// B-frags built in-register (ds_read_b128 + ~10 VALU each: bit -> +-1.0 f16
// via shift/xor into 0xBC00BC00), A-frag = W1^T f16, one
// mfma_f32_16x16x16_f16 per 16-b tile.  Stage-2 = 4 fma + 2 shfl + sigmoid.
// Output transpose fused via LDS tile.  Small per-n state => the 4-n unroll
// software-pipelines within the 128-VGPR budget.
// ---------------------------------------------------------------------------
__global__ __launch_bounds__(256, 4) void mfma_kernel(
    const uint32_t* __restrict__ xpT, const int* __restrict__ neighs,
    const float* __restrict__ W1, const float* __restrict__ b1,
    const float* __restrict__ W2, const float* __restrict__ b2,
    float* __restrict__ out) {
    __shared__ int jtab[4][64];
    __shared__ __align__(16) uint32_t wbuf[4][4][32];  // [wave][ni][wh*16+k]
    __shared__ float tile[64][20];                     // [b_local][n_local]

    const int tid = threadIdx.x;
    const int wv  = __builtin_amdgcn_readfirstlane(tid >> 6);  // wave 0..3
    const int l   = tid & 63;
    const int l15 = l & 15;
    const int lg  = l >> 4;                // 0..3
    const int n0  = blockIdx.x * 16;       // block n range
    const int b0  = blockIdx.y * 64;       // block b range
    const int w0  = blockIdx.y * 2;        // 32-row word-group base

    // wave's 4 n's neighbor indices: jtab[wv][ni*16+k]
    jtab[wv][l] = neighs[(n0 + wv * 4) * KK + l];

#pragma unroll
    for (int ni = 0; ni < 4; ++ni) {
        const int n = n0 + wv * 4 + ni;

        // stage this n's 32 sign-words (2 word-groups x 16 k), lanes 0..31
        if (l < 32) {
            const int j = jtab[wv][ni * 16 + (l & 15)];
            wbuf[wv][ni][l] = xpT[(size_t)j * 16 + w0 + (l >> 4)];
        }

        // A-frag: A[h=l15][k=lg*4+i] = W1[n][k][h]
        const float* W1n = W1 + (size_t)n * (KK * HH) + lg * 4 * HH + l15;
        f16x4 a;
#pragma unroll
        for (int i = 0; i < 4; ++i) a[i] = (f16)W1n[i * HH];

        const float4 b1v = *(const float4*)(b1 + (size_t)n * HH + lg * 4);
        const f32x4 cinit = {b1v.x, b1v.y, b1v.z, b1v.w};
        const float4 w2v = *(const float4*)(W2 + (size_t)n * HH + lg * 4);
        const float b2n = b2[n];

#pragma unroll
        for (int tb = 0; tb < 4; ++tb) {
            const uint4 wk =
                *(const uint4*)&wbuf[wv][ni][(tb >> 1) * 16 + lg * 4];
            const int pos = (tb & 1) * 16 + l15;  // bit index within word
            // bit=1 -> +1.0f16 (0x3C00), bit=0 -> -1.0f16 (0xBC00)
            const uint32_t d0 = 0xBC00BC00u ^ (((wk.x >> pos) & 1u) << 15) ^
                                (((wk.y >> pos) & 1u) << 31);
            const uint32_t d1 = 0xBC00BC00u ^ (((wk.z >> pos) & 1u) << 15) ^
                                (((wk.w >> pos) & 1u) << 31);
            const u32x2 bd = {d0, d1};
            const f16x4 bfr = __builtin_bit_cast(f16x4, bd);

            const f32x4 acc =
                __builtin_amdgcn_mfma_f32_16x16x16f16(a, bfr, cinit, 0, 0, 0);

            float z = fmaf(fmaxf(acc[0], 0.f), w2v.x,
                      fmaf(fmaxf(acc[1], 0.f), w2v.y,
                      fmaf(fmaxf(acc[2], 0.f), w2v.z,
                           fmaxf(acc[3], 0.f) * w2v.w)));
            z += __shfl_xor(z, 16);
            z += __shfl_xor(z, 32);
            z += b2n;
            const float r = 1.0f / (1.0f + __expf(-z));
            if (l < 16) tile[tb * 16 + l][wv * 4 + ni] = r;
        }
    }
    __syncthreads();

    // coalesced-ish store: 4 lanes per b-row write 64B of out[b][n0..n0+15]
    const int row = tid >> 2;
    const int cg  = tid & 3;
    const float4 v = *(const float4*)&tile[row][cg * 4];
    *(float4*)(out + (size_t)(b0 + row) * NN + n0 + cg * 4) = v;
}

// ---------------------------------------------------------------------------
// Fallback scalar kernel (only if workspace is too small).
// ---------------------------------------------------------------------------
__global__ __launch_bounds__(512) void scalar_kernel(
    const float* __restrict__ x, const int* __restrict__ neighs,
    const float* __restrict__ W1, const float* __restrict__ b1,
    const float* __restrict__ W2, const float* __restrict__ b2,
    float* __restrict__ outp) {
    const int n = blockIdx.x;
    const int b = threadIdx.x;
    const int* nb = neighs + n * KK;
    const float* W1n = W1 + (size_t)n * KK * HH;
    const float* b1n = b1 + (size_t)n * HH;
    const float* W2n = W2 + (size_t)n * HH;

    float s[KK];
#pragma unroll
    for (int k = 0; k < KK; ++k) s[k] = x[(size_t)b * NN + nb[k]];

    float acc[HH];
#pragma unroll
    for (int h = 0; h < HH; ++h) acc[h] = b1n[h];
#pragma unroll
    for (int k = 0; k < KK; ++k)
#pragma unroll
        for (int h = 0; h < HH; ++h)
            acc[h] = fmaf(s[k], W1n[k * HH + h], acc[h]);

    float z = b2[n];
#pragma unroll
    for (int h = 0; h < HH; ++h)
        z = fmaf(fmaxf(acc[h], 0.0f), W2n[h], z);
    outp[(size_t)b * NN + n] = 1.0f / (1.0f + __expf(-z));
}

extern "C" void kernel_launch(void* const* d_in, const int* in_sizes, int n_in,
                              void* d_out, int out_size, void* d_ws, size_t ws_size,
                              hipStream_t stream) {
    const float* x      = (const float*)d_in[0];
    const int*   neighs = (const int*)d_in[1];
    const float* W1     = (const float*)d_in[2];
    const float* b1     = (const float*)d_in[3];
    const float* W2     = (const float*)d_in[4];
    const float* b2     = (const float*)d_in[5];
    float* out = (float*)d_out;

    const size_t pack_bytes = (size_t)NN * 16 * sizeof(uint32_t);  // 512 KB

    if (ws_size >= pack_bytes) {
        uint32_t* xpT = (uint32_t*)d_ws;
        pack_kernel<<<dim3(NN / 256, BB / 32), 256, 0, stream>>>(x, xpT);
        mfma_kernel<<<dim3(NN / 16, BB / 64), 256, 0, stream>>>(
            xpT, neighs, W1, b1, W2, b2, out);
    } else {
        scalar_kernel<<<NN, BB, 0, stream>>>(x, neighs, W1, b1, W2, b2, out);
    }
}